// Round 3
// baseline (289.146 us; speedup 1.0000x reference)
//
#include <hip/hip_runtime.h>

// DSR loss: R_t = sum_i w[t,i]*x[t,i];  A_t = c*A_{t-1} + eta*R_t (c=0.99),
// B_t likewise with R^2;  D_t from (A_prev,B_prev);  out = -sum(D)/B.
//
// R5 structure: k1_fused eliminates the cross-lane shuffle chain (R2/R4's
// latency bottleneck: BW scaled as waves x passes-in-flight x 0.5 GB/s;
// the two dependent ds_swizzles per pass made the round-trip huge).
// Each lane writes its fp64 quarter-dot to LDS (fire-and-forget ds_write),
// loads are software-pipelined distance-3 with rotating named registers so
// ~6 KB/wave stays in flight regardless of scheduler mood. Quarter combine
// (q0+q1)+(q2+q3) in phase B is bit-identical to the old shfl_xor order.
// K3 (chunk-prefix scan), K4 (replay + D-sum), K5 (reduce) unchanged logic,
// re-parameterized to CHUNK=1024.

#define D_ETA 0.01
#define D_C   (1.0 - D_ETA)
#define D_EPS 1e-8

constexpr int BLOCK  = 256;
constexpr int CHUNK  = 1024;          // rows per block
constexpr int LPT    = CHUNK / BLOCK; // 4 rows per thread
constexpr int PASSES = CHUNK / 64;    // 16 passes of 64 rows per block

// Hillis-Steele inclusive scan over 256 affine transforms (m, sA, sB).
__device__ __forceinline__ void block_scan(double& m, double& sA, double& sB,
                                           double* mS, double* aS, double* bS) {
    int tid = threadIdx.x;
    mS[tid] = m; aS[tid] = sA; bS[tid] = sB;
    __syncthreads();
#pragma unroll
    for (int off = 1; off < BLOCK; off <<= 1) {
        double pm = 1.0, pa = 0.0, pb = 0.0;
        if (tid >= off) { pm = mS[tid - off]; pa = aS[tid - off]; pb = bS[tid - off]; }
        __syncthreads();
        if (tid >= off) {
            sA = m * pa + sA;
            sB = m * pb + sB;
            m  = pm * m;
        }
        mS[tid] = m; aS[tid] = sA; bS[tid] = sB;
        __syncthreads();
    }
}

// ---------------- K1': dots + chunk aggregate (fused) ----------------
// Phase A: 4 consecutive lanes own one row; per pass the wave issues 2
// perfectly-coalesced 1KB loads. Distance-3 rotating-register pipeline keeps
// ~3 passes (6 KB/wave) in flight; quarter-dot goes to LDS via ds_write_b64
// (no result needed -> no latency on the chain). No cross-lane ops at all.
// Phase B: combine quarters pairwise (bit-identical to old shfl_xor order),
// persist R (coalesced float4), chunk affine aggregate + block scan.
__global__ __launch_bounds__(BLOCK, 4) void k1_fused(
    const float* __restrict__ w, const float* __restrict__ x, int nrows,
    float* __restrict__ Rws,
    double* __restrict__ blkM, double* __restrict__ blkA, double* __restrict__ blkB)
{
    __shared__ double Qs[4][CHUNK];                    // 32 KB, [quarter][row]
    __shared__ double mS[BLOCK], aS[BLOCK], bS[BLOCK]; // 6 KB

    const int tid = threadIdx.x;
    const int b   = blockIdx.x;
    const long long base = (long long)b * CHUNK;
    const int q    = tid & 3;
    const int rsub = tid >> 2;
    const float4* w4 = (const float4*)w;
    const float4* x4 = (const float4*)x;

    const bool full = (base + CHUNK <= (long long)nrows);

    if (full) {
        // float4 index for pass p: base*4 + tid + p*256 (contiguous across tid)
        const long long f0 = base * 4 + tid;
        // distance-3 rotating pipeline: named registers, compile-time rotation
        float4 a0 = w4[f0];
        float4 c0 = x4[f0];
        float4 a1 = w4[f0 + 256];
        float4 c1 = x4[f0 + 256];
        float4 a2 = w4[f0 + 512];
        float4 c2 = x4[f0 + 512];
#pragma unroll
        for (int p = 0; p < PASSES; ++p) {
            float4 a3 = make_float4(0.f, 0.f, 0.f, 0.f);
            float4 c3 = make_float4(0.f, 0.f, 0.f, 0.f);
            if (p + 3 < PASSES) {             // compile-time after unroll
                a3 = w4[f0 + (long long)(p + 3) * 256];
                c3 = x4[f0 + (long long)(p + 3) * 256];
            }
            __builtin_amdgcn_sched_barrier(0); // prefetch issued before consume
            double d = (double)a0.x * c0.x + (double)a0.y * c0.y
                     + (double)a0.z * c0.z + (double)a0.w * c0.w;
            Qs[q][p * 64 + rsub] = d;          // fire-and-forget ds_write_b64
            a0 = a1; c0 = c1;
            a1 = a2; c1 = c2;
            a2 = a3; c2 = c3;
        }
    } else {
        // tail chunk: guarded, no pipeline needed (one block)
        for (int p = 0; p < PASSES; ++p) {
            long long row = base + (long long)p * 64 + rsub;
            if (row < (long long)nrows) {
                long long f = row * 4 + q;
                float4 a = w4[f], c = x4[f];
                Qs[q][p * 64 + rsub] =
                      (double)a.x * c.x + (double)a.y * c.y
                    + (double)a.z * c.z + (double)a.w * c.w;
            }
        }
    }
    __syncthreads();

    // ---- Phase B: combine quarters, persist R, chunk aggregate ----
    long long g0 = base + (long long)tid * LPT;
    long long rem = (long long)nrows - g0;
    int len = rem >= LPT ? LPT : (rem > 0 ? (int)rem : 0);

    float rv[LPT];
#pragma unroll
    for (int r = 0; r < LPT; ++r) {
        int lr = tid * LPT + r;
        double d01 = Qs[0][lr] + Qs[1][lr];   // same order as old xor1
        double d23 = Qs[2][lr] + Qs[3][lr];
        rv[r] = (float)(d01 + d23);           // same order as old xor2
    }

    if (len == LPT) {
        *(float4*)(Rws + g0) = make_float4(rv[0], rv[1], rv[2], rv[3]);
    } else {
        for (int k = 0; k < len; ++k) Rws[g0 + k] = rv[k];
    }

    double m = 1.0, sA = 0.0, sB = 0.0;
    for (int k = 0; k < len; ++k) {
        double r = (double)rv[k];
        sA = D_C * sA + D_ETA * r;
        sB = D_C * sB + D_ETA * (r * r);
        m *= D_C;
    }
    block_scan(m, sA, sB, mS, aS, bS);
    if (tid == BLOCK - 1) {
        blkM[b] = m;
        blkA[b] = sA;
        blkB[b] = sB;
    }
}

// ---------------- fallback helpers (ws too small: recompute R) -------------
__device__ __forceinline__ float row_R(const float* __restrict__ w,
                                       const float* __restrict__ x,
                                       long long row) {
    const float4* w4 = (const float4*)(w + row * 16);
    const float4* x4 = (const float4*)(x + row * 16);
    double d0 = 0.0, d1 = 0.0, d2 = 0.0, d3 = 0.0;
    {
        float4 a = w4[0], b = x4[0];
        d0 = (double)a.x * b.x + (double)a.y * b.y
           + (double)a.z * b.z + (double)a.w * b.w;
    }
    {
        float4 a = w4[1], b = x4[1];
        d1 = (double)a.x * b.x + (double)a.y * b.y
           + (double)a.z * b.z + (double)a.w * b.w;
    }
    {
        float4 a = w4[2], b = x4[2];
        d2 = (double)a.x * b.x + (double)a.y * b.y
           + (double)a.z * b.z + (double)a.w * b.w;
    }
    {
        float4 a = w4[3], b = x4[3];
        d3 = (double)a.x * b.x + (double)a.y * b.y
           + (double)a.z * b.z + (double)a.w * b.w;
    }
    return (float)((d0 + d1) + (d2 + d3));
}

__device__ __forceinline__ int load_seg(const float* __restrict__ Rws,
                                        const float* __restrict__ w,
                                        const float* __restrict__ x,
                                        long long g0, int nrows, float* rv) {
    long long rem = (long long)nrows - g0;
    int len = rem >= LPT ? LPT : (rem > 0 ? (int)rem : 0);
    if (Rws) {
        if (len == LPT) {
            float4 u = *(const float4*)(Rws + g0);
            rv[0] = u.x; rv[1] = u.y; rv[2] = u.z; rv[3] = u.w;
        } else {
            for (int k = 0; k < len; ++k) rv[k] = Rws[g0 + k];
        }
    } else {
        for (int k = 0; k < len; ++k) rv[k] = row_R(w, x, g0 + k);
    }
    return len;
}

// ---------------- K2 (fallback only): per-chunk affine aggregates ----------
__global__ __launch_bounds__(BLOCK) void k2_partials(
    const float* __restrict__ Rws,
    const float* __restrict__ w, const float* __restrict__ x, int nrows,
    double* __restrict__ blkM, double* __restrict__ blkA, double* __restrict__ blkB)
{
    __shared__ double mS[BLOCK], aS[BLOCK], bS[BLOCK];
    int tid = threadIdx.x;
    long long g0 = (long long)blockIdx.x * CHUNK + (long long)tid * LPT;
    float rv[LPT];
    int len = load_seg(Rws, w, x, g0, nrows, rv);

    double m = 1.0, sA = 0.0, sB = 0.0;
    for (int k = 0; k < len; ++k) {
        double r = (double)rv[k];
        sA = D_C * sA + D_ETA * r;
        sB = D_C * sB + D_ETA * (r * r);
        m *= D_C;
    }
    block_scan(m, sA, sB, mS, aS, bS);
    if (tid == BLOCK - 1) {
        blkM[blockIdx.x] = m;
        blkA[blockIdx.x] = sA;
        blkB[blockIdx.x] = sB;
    }
}

// ---------------- K3: scan of chunk aggregates (1 block) ----------------
__global__ __launch_bounds__(BLOCK) void k3_scan(
    int nb,
    const double* __restrict__ blkM, const double* __restrict__ blkA,
    const double* __restrict__ blkB,
    double* __restrict__ A0, double* __restrict__ B0)
{
    __shared__ double mS[BLOCK], aS[BLOCK], bS[BLOCK];
    int tid = threadIdx.x;
    int K = (nb + BLOCK - 1) / BLOCK;
    int g0 = tid * K;
    int g1 = g0 + K; if (g1 > nb) g1 = nb;

    double m = 1.0, sA = 0.0, sB = 0.0;
    for (int g = g0; g < g1; ++g) {
        double mg = blkM[g], ag = blkA[g], bg = blkB[g];
        sA = mg * sA + ag;
        sB = mg * sB + bg;
        m *= mg;
    }
    block_scan(m, sA, sB, mS, aS, bS);

    double em = 1.0, ea = 0.0, eb = 0.0;
    if (tid > 0) { em = mS[tid - 1]; ea = aS[tid - 1]; eb = bS[tid - 1]; }
    double A = ea;                 // em*0 + ea
    double B = em * D_EPS + eb;
    for (int g = g0; g < g1; ++g) {
        A0[g] = A; B0[g] = B;
        double mg = blkM[g], ag = blkA[g], bg = blkB[g];
        A = mg * A + ag;
        B = mg * B + bg;
    }
}

// ---------------- K4: replay + D sum ----------------
__global__ __launch_bounds__(BLOCK) void k4_dsum(
    const float* __restrict__ Rws,
    const float* __restrict__ w, const float* __restrict__ x, int nrows,
    const double* __restrict__ A0, const double* __restrict__ B0,
    double* __restrict__ bsum)
{
    __shared__ double mS[BLOCK], aS[BLOCK], bS[BLOCK];
    __shared__ double wsum[BLOCK / 64];
    int tid = threadIdx.x;
    long long g0 = (long long)blockIdx.x * CHUNK + (long long)tid * LPT;
    float rv[LPT];
    int len = load_seg(Rws, w, x, g0, nrows, rv);

    double m = 1.0, sA = 0.0, sB = 0.0;
    for (int k = 0; k < len; ++k) {
        double r = (double)rv[k];
        sA = D_C * sA + D_ETA * r;
        sB = D_C * sB + D_ETA * (r * r);
        m *= D_C;
    }
    block_scan(m, sA, sB, mS, aS, bS);

    double em = 1.0, ea = 0.0, eb = 0.0;
    if (tid > 0) { em = mS[tid - 1]; ea = aS[tid - 1]; eb = bS[tid - 1]; }
    double A = em * A0[blockIdx.x] + ea;
    double B = em * B0[blockIdx.x] + eb;

    double dsum = 0.0;
    for (int k = 0; k < len; ++k) {
        double r = (double)rv[k];
        double dA = D_ETA * (r - A);
        double dB = D_ETA * (r * r - B);
        double var = B - A * A;
        if (var < D_EPS) var = D_EPS;
        double denom = var * sqrt(var);
        dsum += (B * dA - 0.5 * A * dB) / denom;
        A += dA;
        B += dB;
    }

#pragma unroll
    for (int off = 32; off > 0; off >>= 1) dsum += __shfl_down(dsum, off, 64);
    if ((tid & 63) == 0) wsum[tid >> 6] = dsum;
    __syncthreads();
    if (tid == 0) bsum[blockIdx.x] = wsum[0] + wsum[1] + wsum[2] + wsum[3];
}

// ---------------- K5: final reduction ----------------
__global__ __launch_bounds__(BLOCK) void k5_final(
    const double* __restrict__ bsum, int nb, int nrows, float* __restrict__ out)
{
    __shared__ double sh[BLOCK / 64];
    int tid = threadIdx.x;
    double s = 0.0;
    for (int i = tid; i < nb; i += BLOCK) s += bsum[i];
#pragma unroll
    for (int off = 32; off > 0; off >>= 1) s += __shfl_down(s, off, 64);
    if ((tid & 63) == 0) sh[tid >> 6] = s;
    __syncthreads();
    if (tid == 0) out[0] = (float)(-(sh[0] + sh[1] + sh[2] + sh[3]) / (double)nrows);
}

extern "C" void kernel_launch(void* const* d_in, const int* in_sizes, int n_in,
                              void* d_out, int out_size, void* d_ws, size_t ws_size,
                              hipStream_t stream)
{
    const float* w = (const float*)d_in[0];
    const float* x = (const float*)d_in[1];
    int nrows = in_sizes[0] / 16;
    int nb  = (nrows + CHUNK - 1) / CHUNK;

    char* ws = (char*)d_ws;
    double* blkM = (double*)(ws + 64);
    double* blkA = blkM + nb;
    double* blkB = blkA + nb;
    double* A0   = blkB + nb;
    double* B0   = A0 + nb;
    double* bsum = B0 + nb;

    size_t off = 64 + (size_t)6 * nb * sizeof(double);
    off = (off + 255) & ~(size_t)255;
    float* Rws = nullptr;
    if (ws_size >= off + (size_t)nrows * sizeof(float))
        Rws = (float*)(ws + off);

    if (Rws) {
        // fused K1+K2: single pass over w,x; R persisted once
        k1_fused<<<nb, BLOCK, 0, stream>>>(w, x, nrows, Rws, blkM, blkA, blkB);
    } else {
        k2_partials<<<nb, BLOCK, 0, stream>>>(Rws, w, x, nrows, blkM, blkA, blkB);
    }
    k3_scan<<<1, BLOCK, 0, stream>>>(nb, blkM, blkA, blkB, A0, B0);
    k4_dsum<<<nb, BLOCK, 0, stream>>>(Rws, w, x, nrows, A0, B0, bsum);
    k5_final<<<1, BLOCK, 0, stream>>>(bsum, nb, nrows, (float*)d_out);
}

// Round 4
// 267.755 us; speedup vs baseline: 1.0799x; 1.0799x over previous
//
#include <hip/hip_runtime.h>

// DSR loss: R_t = sum_i w[t,i]*x[t,i];  A_t = c*A_{t-1} + eta*R_t (c=0.99),
// B_t likewise with R^2;  D_t from (A_prev,B_prev);  out = -sum(D)/B.
//
// R6: R5 structure (distance-3 rotating load pipeline, fp64 quarter-dots to
// LDS, no cross-lane ops) + NON-TEMPORAL loads on the w/x streams.
// Evidence: K1 is pinned at one 2KB wave-pass per ~240 cy/CU (8.5 B/cy/CU)
// invariant to occupancy (30-68%), depth (1-3), and combine mechanism
// (shfl vs LDS); L3-warm runs are equally slow -> the wall is the per-CU
// load-return path, not HBM. Streams have zero reuse, so 'nt' (bypass L1
// allocation) targets the remaining suspect: L1 line-allocation churn.
// K3 (chunk-prefix scan), K4 (replay + D-sum), K5 (reduce) unchanged.

#define D_ETA 0.01
#define D_C   (1.0 - D_ETA)
#define D_EPS 1e-8

constexpr int BLOCK  = 256;
constexpr int CHUNK  = 1024;          // rows per block
constexpr int LPT    = CHUNK / BLOCK; // 4 rows per thread
constexpr int PASSES = CHUNK / 64;    // 16 passes of 64 rows per block

// native clang vector type: __builtin_nontemporal_load needs scalar/vector,
// HIP's float4 is a struct and won't do.
typedef float f32x4 __attribute__((ext_vector_type(4)));

// Hillis-Steele inclusive scan over 256 affine transforms (m, sA, sB).
__device__ __forceinline__ void block_scan(double& m, double& sA, double& sB,
                                           double* mS, double* aS, double* bS) {
    int tid = threadIdx.x;
    mS[tid] = m; aS[tid] = sA; bS[tid] = sB;
    __syncthreads();
#pragma unroll
    for (int off = 1; off < BLOCK; off <<= 1) {
        double pm = 1.0, pa = 0.0, pb = 0.0;
        if (tid >= off) { pm = mS[tid - off]; pa = aS[tid - off]; pb = bS[tid - off]; }
        __syncthreads();
        if (tid >= off) {
            sA = m * pa + sA;
            sB = m * pb + sB;
            m  = pm * m;
        }
        mS[tid] = m; aS[tid] = sA; bS[tid] = sB;
        __syncthreads();
    }
}

// ---------------- K1': dots + chunk aggregate (fused) ----------------
// Phase A: 4 consecutive lanes own one row; per pass the wave issues 2
// perfectly-coalesced 1KB NT loads. Distance-3 rotating-register pipeline
// keeps ~3 passes (6 KB/wave) in flight; quarter-dot goes to LDS via
// ds_write_b64 (fire-and-forget). No cross-lane ops.
// Phase B: combine quarters pairwise (bit-identical to the original
// shfl_xor reduction order), persist R, chunk affine aggregate + scan.
__global__ __launch_bounds__(BLOCK, 4) void k1_fused(
    const float* __restrict__ w, const float* __restrict__ x, int nrows,
    float* __restrict__ Rws,
    double* __restrict__ blkM, double* __restrict__ blkA, double* __restrict__ blkB)
{
    __shared__ double Qs[4][CHUNK];                    // 32 KB, [quarter][row]
    __shared__ double mS[BLOCK], aS[BLOCK], bS[BLOCK]; // 6 KB

    const int tid = threadIdx.x;
    const int b   = blockIdx.x;
    const long long base = (long long)b * CHUNK;
    const int q    = tid & 3;
    const int rsub = tid >> 2;
    const f32x4* w4 = (const f32x4*)w;
    const f32x4* x4 = (const f32x4*)x;

    const bool full = (base + CHUNK <= (long long)nrows);

    if (full) {
        // float4 index for pass p: base*4 + tid + p*256 (contiguous across tid)
        const long long f0 = base * 4 + tid;
        // distance-3 rotating pipeline: named registers, compile-time rotation
        f32x4 a0 = __builtin_nontemporal_load(&w4[f0]);
        f32x4 c0 = __builtin_nontemporal_load(&x4[f0]);
        f32x4 a1 = __builtin_nontemporal_load(&w4[f0 + 256]);
        f32x4 c1 = __builtin_nontemporal_load(&x4[f0 + 256]);
        f32x4 a2 = __builtin_nontemporal_load(&w4[f0 + 512]);
        f32x4 c2 = __builtin_nontemporal_load(&x4[f0 + 512]);
#pragma unroll
        for (int p = 0; p < PASSES; ++p) {
            f32x4 a3 = (f32x4)(0.f);
            f32x4 c3 = (f32x4)(0.f);
            if (p + 3 < PASSES) {             // compile-time after unroll
                a3 = __builtin_nontemporal_load(&w4[f0 + (long long)(p + 3) * 256]);
                c3 = __builtin_nontemporal_load(&x4[f0 + (long long)(p + 3) * 256]);
            }
            __builtin_amdgcn_sched_barrier(0); // prefetch issued before consume
            double d = (double)a0.x * c0.x + (double)a0.y * c0.y
                     + (double)a0.z * c0.z + (double)a0.w * c0.w;
            Qs[q][p * 64 + rsub] = d;          // fire-and-forget ds_write_b64
            a0 = a1; c0 = c1;
            a1 = a2; c1 = c2;
            a2 = a3; c2 = c3;
        }
    } else {
        // tail chunk: guarded, no pipeline needed (one block)
        for (int p = 0; p < PASSES; ++p) {
            long long row = base + (long long)p * 64 + rsub;
            if (row < (long long)nrows) {
                long long f = row * 4 + q;
                f32x4 a = w4[f], c = x4[f];
                Qs[q][p * 64 + rsub] =
                      (double)a.x * c.x + (double)a.y * c.y
                    + (double)a.z * c.z + (double)a.w * c.w;
            }
        }
    }
    __syncthreads();

    // ---- Phase B: combine quarters, persist R, chunk aggregate ----
    long long g0 = base + (long long)tid * LPT;
    long long rem = (long long)nrows - g0;
    int len = rem >= LPT ? LPT : (rem > 0 ? (int)rem : 0);

    float rv[LPT];
#pragma unroll
    for (int r = 0; r < LPT; ++r) {
        int lr = tid * LPT + r;
        double d01 = Qs[0][lr] + Qs[1][lr];   // same order as old xor1
        double d23 = Qs[2][lr] + Qs[3][lr];
        rv[r] = (float)(d01 + d23);           // same order as old xor2
    }

    if (len == LPT) {
        *(float4*)(Rws + g0) = make_float4(rv[0], rv[1], rv[2], rv[3]);
    } else {
        for (int k = 0; k < len; ++k) Rws[g0 + k] = rv[k];
    }

    double m = 1.0, sA = 0.0, sB = 0.0;
    for (int k = 0; k < len; ++k) {
        double r = (double)rv[k];
        sA = D_C * sA + D_ETA * r;
        sB = D_C * sB + D_ETA * (r * r);
        m *= D_C;
    }
    block_scan(m, sA, sB, mS, aS, bS);
    if (tid == BLOCK - 1) {
        blkM[b] = m;
        blkA[b] = sA;
        blkB[b] = sB;
    }
}

// ---------------- fallback helpers (ws too small: recompute R) -------------
__device__ __forceinline__ float row_R(const float* __restrict__ w,
                                       const float* __restrict__ x,
                                       long long row) {
    const float4* w4 = (const float4*)(w + row * 16);
    const float4* x4 = (const float4*)(x + row * 16);
    double d0 = 0.0, d1 = 0.0, d2 = 0.0, d3 = 0.0;
    {
        float4 a = w4[0], b = x4[0];
        d0 = (double)a.x * b.x + (double)a.y * b.y
           + (double)a.z * b.z + (double)a.w * b.w;
    }
    {
        float4 a = w4[1], b = x4[1];
        d1 = (double)a.x * b.x + (double)a.y * b.y
           + (double)a.z * b.z + (double)a.w * b.w;
    }
    {
        float4 a = w4[2], b = x4[2];
        d2 = (double)a.x * b.x + (double)a.y * b.y
           + (double)a.z * b.z + (double)a.w * b.w;
    }
    {
        float4 a = w4[3], b = x4[3];
        d3 = (double)a.x * b.x + (double)a.y * b.y
           + (double)a.z * b.z + (double)a.w * b.w;
    }
    return (float)((d0 + d1) + (d2 + d3));
}

__device__ __forceinline__ int load_seg(const float* __restrict__ Rws,
                                        const float* __restrict__ w,
                                        const float* __restrict__ x,
                                        long long g0, int nrows, float* rv) {
    long long rem = (long long)nrows - g0;
    int len = rem >= LPT ? LPT : (rem > 0 ? (int)rem : 0);
    if (Rws) {
        if (len == LPT) {
            float4 u = *(const float4*)(Rws + g0);
            rv[0] = u.x; rv[1] = u.y; rv[2] = u.z; rv[3] = u.w;
        } else {
            for (int k = 0; k < len; ++k) rv[k] = Rws[g0 + k];
        }
    } else {
        for (int k = 0; k < len; ++k) rv[k] = row_R(w, x, g0 + k);
    }
    return len;
}

// ---------------- K2 (fallback only): per-chunk affine aggregates ----------
__global__ __launch_bounds__(BLOCK) void k2_partials(
    const float* __restrict__ Rws,
    const float* __restrict__ w, const float* __restrict__ x, int nrows,
    double* __restrict__ blkM, double* __restrict__ blkA, double* __restrict__ blkB)
{
    __shared__ double mS[BLOCK], aS[BLOCK], bS[BLOCK];
    int tid = threadIdx.x;
    long long g0 = (long long)blockIdx.x * CHUNK + (long long)tid * LPT;
    float rv[LPT];
    int len = load_seg(Rws, w, x, g0, nrows, rv);

    double m = 1.0, sA = 0.0, sB = 0.0;
    for (int k = 0; k < len; ++k) {
        double r = (double)rv[k];
        sA = D_C * sA + D_ETA * r;
        sB = D_C * sB + D_ETA * (r * r);
        m *= D_C;
    }
    block_scan(m, sA, sB, mS, aS, bS);
    if (tid == BLOCK - 1) {
        blkM[blockIdx.x] = m;
        blkA[blockIdx.x] = sA;
        blkB[blockIdx.x] = sB;
    }
}

// ---------------- K3: scan of chunk aggregates (1 block) ----------------
__global__ __launch_bounds__(BLOCK) void k3_scan(
    int nb,
    const double* __restrict__ blkM, const double* __restrict__ blkA,
    const double* __restrict__ blkB,
    double* __restrict__ A0, double* __restrict__ B0)
{
    __shared__ double mS[BLOCK], aS[BLOCK], bS[BLOCK];
    int tid = threadIdx.x;
    int K = (nb + BLOCK - 1) / BLOCK;
    int g0 = tid * K;
    int g1 = g0 + K; if (g1 > nb) g1 = nb;

    double m = 1.0, sA = 0.0, sB = 0.0;
    for (int g = g0; g < g1; ++g) {
        double mg = blkM[g], ag = blkA[g], bg = blkB[g];
        sA = mg * sA + ag;
        sB = mg * sB + bg;
        m *= mg;
    }
    block_scan(m, sA, sB, mS, aS, bS);

    double em = 1.0, ea = 0.0, eb = 0.0;
    if (tid > 0) { em = mS[tid - 1]; ea = aS[tid - 1]; eb = bS[tid - 1]; }
    double A = ea;                 // em*0 + ea
    double B = em * D_EPS + eb;
    for (int g = g0; g < g1; ++g) {
        A0[g] = A; B0[g] = B;
        double mg = blkM[g], ag = blkA[g], bg = blkB[g];
        A = mg * A + ag;
        B = mg * B + bg;
    }
}

// ---------------- K4: replay + D sum ----------------
__global__ __launch_bounds__(BLOCK) void k4_dsum(
    const float* __restrict__ Rws,
    const float* __restrict__ w, const float* __restrict__ x, int nrows,
    const double* __restrict__ A0, const double* __restrict__ B0,
    double* __restrict__ bsum)
{
    __shared__ double mS[BLOCK], aS[BLOCK], bS[BLOCK];
    __shared__ double wsum[BLOCK / 64];
    int tid = threadIdx.x;
    long long g0 = (long long)blockIdx.x * CHUNK + (long long)tid * LPT;
    float rv[LPT];
    int len = load_seg(Rws, w, x, g0, nrows, rv);

    double m = 1.0, sA = 0.0, sB = 0.0;
    for (int k = 0; k < len; ++k) {
        double r = (double)rv[k];
        sA = D_C * sA + D_ETA * r;
        sB = D_C * sB + D_ETA * (r * r);
        m *= D_C;
    }
    block_scan(m, sA, sB, mS, aS, bS);

    double em = 1.0, ea = 0.0, eb = 0.0;
    if (tid > 0) { em = mS[tid - 1]; ea = aS[tid - 1]; eb = bS[tid - 1]; }
    double A = em * A0[blockIdx.x] + ea;
    double B = em * B0[blockIdx.x] + eb;

    double dsum = 0.0;
    for (int k = 0; k < len; ++k) {
        double r = (double)rv[k];
        double dA = D_ETA * (r - A);
        double dB = D_ETA * (r * r - B);
        double var = B - A * A;
        if (var < D_EPS) var = D_EPS;
        double denom = var * sqrt(var);
        dsum += (B * dA - 0.5 * A * dB) / denom;
        A += dA;
        B += dB;
    }

#pragma unroll
    for (int off = 32; off > 0; off >>= 1) dsum += __shfl_down(dsum, off, 64);
    if ((tid & 63) == 0) wsum[tid >> 6] = dsum;
    __syncthreads();
    if (tid == 0) bsum[blockIdx.x] = wsum[0] + wsum[1] + wsum[2] + wsum[3];
}

// ---------------- K5: final reduction ----------------
__global__ __launch_bounds__(BLOCK) void k5_final(
    const double* __restrict__ bsum, int nb, int nrows, float* __restrict__ out)
{
    __shared__ double sh[BLOCK / 64];
    int tid = threadIdx.x;
    double s = 0.0;
    for (int i = tid; i < nb; i += BLOCK) s += bsum[i];
#pragma unroll
    for (int off = 32; off > 0; off >>= 1) s += __shfl_down(s, off, 64);
    if ((tid & 63) == 0) sh[tid >> 6] = s;
    __syncthreads();
    if (tid == 0) out[0] = (float)(-(sh[0] + sh[1] + sh[2] + sh[3]) / (double)nrows);
}

extern "C" void kernel_launch(void* const* d_in, const int* in_sizes, int n_in,
                              void* d_out, int out_size, void* d_ws, size_t ws_size,
                              hipStream_t stream)
{
    const float* w = (const float*)d_in[0];
    const float* x = (const float*)d_in[1];
    int nrows = in_sizes[0] / 16;
    int nb  = (nrows + CHUNK - 1) / CHUNK;

    char* ws = (char*)d_ws;
    double* blkM = (double*)(ws + 64);
    double* blkA = blkM + nb;
    double* blkB = blkA + nb;
    double* A0   = blkB + nb;
    double* B0   = A0 + nb;
    double* bsum = B0 + nb;

    size_t off = 64 + (size_t)6 * nb * sizeof(double);
    off = (off + 255) & ~(size_t)255;
    float* Rws = nullptr;
    if (ws_size >= off + (size_t)nrows * sizeof(float))
        Rws = (float*)(ws + off);

    if (Rws) {
        // fused K1+K2: single pass over w,x; R persisted once
        k1_fused<<<nb, BLOCK, 0, stream>>>(w, x, nrows, Rws, blkM, blkA, blkB);
    } else {
        k2_partials<<<nb, BLOCK, 0, stream>>>(Rws, w, x, nrows, blkM, blkA, blkB);
    }
    k3_scan<<<1, BLOCK, 0, stream>>>(nb, blkM, blkA, blkB, A0, B0);
    k4_dsum<<<nb, BLOCK, 0, stream>>>(Rws, w, x, nrows, A0, B0, bsum);
    k5_final<<<1, BLOCK, 0, stream>>>(bsum, nb, nrows, (float*)d_out);
}

// Round 5
// 267.501 us; speedup vs baseline: 1.0809x; 1.0010x over previous
//
#include <hip/hip_runtime.h>

// DSR loss: R_t = sum_i w[t,i]*x[t,i];  A_t = c*A_{t-1} + eta*R_t (c=0.99),
// B_t likewise with R^2;  D_t from (A_prev,B_prev);  out = -sum(D)/B.
//
// R7: R6 (nt loads, rotating pipeline, fp64 quarter-dots) + concurrency push:
// depth 3->4, and Qs halved to [2][CHUNK] via a single shfl_xor(1) pair-
// combine (bit-identical reduction order), LDS 38.9->22.5 KB -> 7 blocks/CU.
// Evidence trail: BW ∝ waves/CU x passes-in-flight (R2/R4/R5); nt broke the
// L1-churn component (k1 101 -> <74 us); now raise both concurrency factors
// to reach the ~40 us HBM floor (fills calibrate 6.9 TB/s achievable).
// K3 (chunk-prefix scan), K4 (replay + D-sum, nt R read), K5 unchanged.

#define D_ETA 0.01
#define D_C   (1.0 - D_ETA)
#define D_EPS 1e-8

constexpr int BLOCK  = 256;
constexpr int CHUNK  = 1024;          // rows per block
constexpr int LPT    = CHUNK / BLOCK; // 4 rows per thread
constexpr int PASSES = CHUNK / 64;    // 16 passes of 64 rows per block

// native clang vector type: __builtin_nontemporal_load needs scalar/vector.
typedef float f32x4 __attribute__((ext_vector_type(4)));

// Hillis-Steele inclusive scan over 256 affine transforms (m, sA, sB).
__device__ __forceinline__ void block_scan(double& m, double& sA, double& sB,
                                           double* mS, double* aS, double* bS) {
    int tid = threadIdx.x;
    mS[tid] = m; aS[tid] = sA; bS[tid] = sB;
    __syncthreads();
#pragma unroll
    for (int off = 1; off < BLOCK; off <<= 1) {
        double pm = 1.0, pa = 0.0, pb = 0.0;
        if (tid >= off) { pm = mS[tid - off]; pa = aS[tid - off]; pb = bS[tid - off]; }
        __syncthreads();
        if (tid >= off) {
            sA = m * pa + sA;
            sB = m * pb + sB;
            m  = pm * m;
        }
        mS[tid] = m; aS[tid] = sA; bS[tid] = sB;
        __syncthreads();
    }
}

// ---------------- K1': dots + chunk aggregate (fused) ----------------
// Phase A: 4 consecutive lanes own one row; per pass the wave issues 2
// coalesced 1KB NT loads. Distance-4 rotating pipeline (~8 KB/wave in
// flight). Pair-combine with ONE shfl_xor(1) (old xor-1 step), lanes q=0/2
// write d01/d23 to Qs[0/1] (fire-and-forget ds_write_b64).
// Phase B: rv = (float)(d01 + d23) -- identical bracket order to the
// original shfl reduction; persist R, chunk affine aggregate + scan.
__global__ __launch_bounds__(BLOCK, 6) void k1_fused(
    const float* __restrict__ w, const float* __restrict__ x, int nrows,
    float* __restrict__ Rws,
    double* __restrict__ blkM, double* __restrict__ blkA, double* __restrict__ blkB)
{
    __shared__ double Qs[2][CHUNK];                    // 16 KB, [pair][row]
    __shared__ double mS[BLOCK], aS[BLOCK], bS[BLOCK]; // 6 KB

    const int tid = threadIdx.x;
    const int b   = blockIdx.x;
    const long long base = (long long)b * CHUNK;
    const int q    = tid & 3;
    const int rsub = tid >> 2;
    const f32x4* w4 = (const f32x4*)w;
    const f32x4* x4 = (const f32x4*)x;

    const bool full = (base + CHUNK <= (long long)nrows);

    if (full) {
        // float4 index for pass p: base*4 + tid + p*256 (contiguous across tid)
        const long long f0 = base * 4 + tid;
        // distance-4 rotating pipeline: named registers, compile-time rotation
        f32x4 a0 = __builtin_nontemporal_load(&w4[f0]);
        f32x4 c0 = __builtin_nontemporal_load(&x4[f0]);
        f32x4 a1 = __builtin_nontemporal_load(&w4[f0 + 256]);
        f32x4 c1 = __builtin_nontemporal_load(&x4[f0 + 256]);
        f32x4 a2 = __builtin_nontemporal_load(&w4[f0 + 512]);
        f32x4 c2 = __builtin_nontemporal_load(&x4[f0 + 512]);
        f32x4 a3 = __builtin_nontemporal_load(&w4[f0 + 768]);
        f32x4 c3 = __builtin_nontemporal_load(&x4[f0 + 768]);
#pragma unroll
        for (int p = 0; p < PASSES; ++p) {
            f32x4 an = (f32x4)(0.f);
            f32x4 cn = (f32x4)(0.f);
            if (p + 4 < PASSES) {             // compile-time after unroll
                an = __builtin_nontemporal_load(&w4[f0 + (long long)(p + 4) * 256]);
                cn = __builtin_nontemporal_load(&x4[f0 + (long long)(p + 4) * 256]);
            }
            __builtin_amdgcn_sched_barrier(0); // prefetch issued before consume
            double d = (double)a0.x * c0.x + (double)a0.y * c0.y
                     + (double)a0.z * c0.z + (double)a0.w * c0.w;
            d += __shfl_xor(d, 1, 64);         // d01 on q=0/1, d23 on q=2/3
            if ((q & 1) == 0)
                Qs[q >> 1][p * 64 + rsub] = d; // fire-and-forget ds_write_b64
            a0 = a1; c0 = c1;
            a1 = a2; c1 = c2;
            a2 = a3; c2 = c3;
            a3 = an; c3 = cn;
        }
    } else {
        // tail chunk: guarded loads, shfl stays wave-uniform
        for (int p = 0; p < PASSES; ++p) {
            long long row = base + (long long)p * 64 + rsub;
            double d = 0.0;
            if (row < (long long)nrows) {
                long long f = row * 4 + q;
                f32x4 a = w4[f], c = x4[f];
                d = (double)a.x * c.x + (double)a.y * c.y
                  + (double)a.z * c.z + (double)a.w * c.w;
            }
            d += __shfl_xor(d, 1, 64);
            if ((q & 1) == 0 && row < (long long)nrows)
                Qs[q >> 1][p * 64 + rsub] = d;
        }
    }
    __syncthreads();

    // ---- Phase B: combine pairs, persist R, chunk aggregate ----
    long long g0 = base + (long long)tid * LPT;
    long long rem = (long long)nrows - g0;
    int len = rem >= LPT ? LPT : (rem > 0 ? (int)rem : 0);

    float rv[LPT];
#pragma unroll
    for (int r = 0; r < LPT; ++r) {
        int lr = tid * LPT + r;
        rv[r] = (float)(Qs[0][lr] + Qs[1][lr]); // (d0+d1)+(d2+d3) order
    }

    if (len == LPT) {
        *(float4*)(Rws + g0) = make_float4(rv[0], rv[1], rv[2], rv[3]);
    } else {
        for (int k = 0; k < len; ++k) Rws[g0 + k] = rv[k];
    }

    double m = 1.0, sA = 0.0, sB = 0.0;
    for (int k = 0; k < len; ++k) {
        double r = (double)rv[k];
        sA = D_C * sA + D_ETA * r;
        sB = D_C * sB + D_ETA * (r * r);
        m *= D_C;
    }
    block_scan(m, sA, sB, mS, aS, bS);
    if (tid == BLOCK - 1) {
        blkM[b] = m;
        blkA[b] = sA;
        blkB[b] = sB;
    }
}

// ---------------- fallback helpers (ws too small: recompute R) -------------
__device__ __forceinline__ float row_R(const float* __restrict__ w,
                                       const float* __restrict__ x,
                                       long long row) {
    const float4* w4 = (const float4*)(w + row * 16);
    const float4* x4 = (const float4*)(x + row * 16);
    double d0, d1, d2, d3;
    {
        float4 a = w4[0], b = x4[0];
        d0 = (double)a.x * b.x + (double)a.y * b.y
           + (double)a.z * b.z + (double)a.w * b.w;
    }
    {
        float4 a = w4[1], b = x4[1];
        d1 = (double)a.x * b.x + (double)a.y * b.y
           + (double)a.z * b.z + (double)a.w * b.w;
    }
    {
        float4 a = w4[2], b = x4[2];
        d2 = (double)a.x * b.x + (double)a.y * b.y
           + (double)a.z * b.z + (double)a.w * b.w;
    }
    {
        float4 a = w4[3], b = x4[3];
        d3 = (double)a.x * b.x + (double)a.y * b.y
           + (double)a.z * b.z + (double)a.w * b.w;
    }
    return (float)((d0 + d1) + (d2 + d3));
}

__device__ __forceinline__ int load_seg(const float* __restrict__ Rws,
                                        const float* __restrict__ w,
                                        const float* __restrict__ x,
                                        long long g0, int nrows, float* rv) {
    long long rem = (long long)nrows - g0;
    int len = rem >= LPT ? LPT : (rem > 0 ? (int)rem : 0);
    if (Rws) {
        if (len == LPT) {
            f32x4 u = __builtin_nontemporal_load((const f32x4*)(Rws + g0));
            rv[0] = u.x; rv[1] = u.y; rv[2] = u.z; rv[3] = u.w;
        } else {
            for (int k = 0; k < len; ++k) rv[k] = Rws[g0 + k];
        }
    } else {
        for (int k = 0; k < len; ++k) rv[k] = row_R(w, x, g0 + k);
    }
    return len;
}

// ---------------- K2 (fallback only): per-chunk affine aggregates ----------
__global__ __launch_bounds__(BLOCK) void k2_partials(
    const float* __restrict__ Rws,
    const float* __restrict__ w, const float* __restrict__ x, int nrows,
    double* __restrict__ blkM, double* __restrict__ blkA, double* __restrict__ blkB)
{
    __shared__ double mS[BLOCK], aS[BLOCK], bS[BLOCK];
    int tid = threadIdx.x;
    long long g0 = (long long)blockIdx.x * CHUNK + (long long)tid * LPT;
    float rv[LPT];
    int len = load_seg(Rws, w, x, g0, nrows, rv);

    double m = 1.0, sA = 0.0, sB = 0.0;
    for (int k = 0; k < len; ++k) {
        double r = (double)rv[k];
        sA = D_C * sA + D_ETA * r;
        sB = D_C * sB + D_ETA * (r * r);
        m *= D_C;
    }
    block_scan(m, sA, sB, mS, aS, bS);
    if (tid == BLOCK - 1) {
        blkM[blockIdx.x] = m;
        blkA[blockIdx.x] = sA;
        blkB[blockIdx.x] = sB;
    }
}

// ---------------- K3: scan of chunk aggregates (1 block) ----------------
__global__ __launch_bounds__(BLOCK) void k3_scan(
    int nb,
    const double* __restrict__ blkM, const double* __restrict__ blkA,
    const double* __restrict__ blkB,
    double* __restrict__ A0, double* __restrict__ B0)
{
    __shared__ double mS[BLOCK], aS[BLOCK], bS[BLOCK];
    int tid = threadIdx.x;
    int K = (nb + BLOCK - 1) / BLOCK;
    int g0 = tid * K;
    int g1 = g0 + K; if (g1 > nb) g1 = nb;

    double m = 1.0, sA = 0.0, sB = 0.0;
    for (int g = g0; g < g1; ++g) {
        double mg = blkM[g], ag = blkA[g], bg = blkB[g];
        sA = mg * sA + ag;
        sB = mg * sB + bg;
        m *= mg;
    }
    block_scan(m, sA, sB, mS, aS, bS);

    double em = 1.0, ea = 0.0, eb = 0.0;
    if (tid > 0) { em = mS[tid - 1]; ea = aS[tid - 1]; eb = bS[tid - 1]; }
    double A = ea;                 // em*0 + ea
    double B = em * D_EPS + eb;
    for (int g = g0; g < g1; ++g) {
        A0[g] = A; B0[g] = B;
        double mg = blkM[g], ag = blkA[g], bg = blkB[g];
        A = mg * A + ag;
        B = mg * B + bg;
    }
}

// ---------------- K4: replay + D sum ----------------
__global__ __launch_bounds__(BLOCK) void k4_dsum(
    const float* __restrict__ Rws,
    const float* __restrict__ w, const float* __restrict__ x, int nrows,
    const double* __restrict__ A0, const double* __restrict__ B0,
    double* __restrict__ bsum)
{
    __shared__ double mS[BLOCK], aS[BLOCK], bS[BLOCK];
    __shared__ double wsum[BLOCK / 64];
    int tid = threadIdx.x;
    long long g0 = (long long)blockIdx.x * CHUNK + (long long)tid * LPT;
    float rv[LPT];
    int len = load_seg(Rws, w, x, g0, nrows, rv);

    double m = 1.0, sA = 0.0, sB = 0.0;
    for (int k = 0; k < len; ++k) {
        double r = (double)rv[k];
        sA = D_C * sA + D_ETA * r;
        sB = D_C * sB + D_ETA * (r * r);
        m *= D_C;
    }
    block_scan(m, sA, sB, mS, aS, bS);

    double em = 1.0, ea = 0.0, eb = 0.0;
    if (tid > 0) { em = mS[tid - 1]; ea = aS[tid - 1]; eb = bS[tid - 1]; }
    double A = em * A0[blockIdx.x] + ea;
    double B = em * B0[blockIdx.x] + eb;

    double dsum = 0.0;
    for (int k = 0; k < len; ++k) {
        double r = (double)rv[k];
        double dA = D_ETA * (r - A);
        double dB = D_ETA * (r * r - B);
        double var = B - A * A;
        if (var < D_EPS) var = D_EPS;
        double denom = var * sqrt(var);
        dsum += (B * dA - 0.5 * A * dB) / denom;
        A += dA;
        B += dB;
    }

#pragma unroll
    for (int off = 32; off > 0; off >>= 1) dsum += __shfl_down(dsum, off, 64);
    if ((tid & 63) == 0) wsum[tid >> 6] = dsum;
    __syncthreads();
    if (tid == 0) bsum[blockIdx.x] = wsum[0] + wsum[1] + wsum[2] + wsum[3];
}

// ---------------- K5: final reduction ----------------
__global__ __launch_bounds__(BLOCK) void k5_final(
    const double* __restrict__ bsum, int nb, int nrows, float* __restrict__ out)
{
    __shared__ double sh[BLOCK / 64];
    int tid = threadIdx.x;
    double s = 0.0;
    for (int i = tid; i < nb; i += BLOCK) s += bsum[i];
#pragma unroll
    for (int off = 32; off > 0; off >>= 1) s += __shfl_down(s, off, 64);
    if ((tid & 63) == 0) sh[tid >> 6] = s;
    __syncthreads();
    if (tid == 0) out[0] = (float)(-(sh[0] + sh[1] + sh[2] + sh[3]) / (double)nrows);
}

extern "C" void kernel_launch(void* const* d_in, const int* in_sizes, int n_in,
                              void* d_out, int out_size, void* d_ws, size_t ws_size,
                              hipStream_t stream)
{
    const float* w = (const float*)d_in[0];
    const float* x = (const float*)d_in[1];
    int nrows = in_sizes[0] / 16;
    int nb  = (nrows + CHUNK - 1) / CHUNK;

    char* ws = (char*)d_ws;
    double* blkM = (double*)(ws + 64);
    double* blkA = blkM + nb;
    double* blkB = blkA + nb;
    double* A0   = blkB + nb;
    double* B0   = A0 + nb;
    double* bsum = B0 + nb;

    size_t off = 64 + (size_t)6 * nb * sizeof(double);
    off = (off + 255) & ~(size_t)255;
    float* Rws = nullptr;
    if (ws_size >= off + (size_t)nrows * sizeof(float))
        Rws = (float*)(ws + off);

    if (Rws) {
        // fused K1+K2: single pass over w,x; R persisted once
        k1_fused<<<nb, BLOCK, 0, stream>>>(w, x, nrows, Rws, blkM, blkA, blkB);
    } else {
        k2_partials<<<nb, BLOCK, 0, stream>>>(Rws, w, x, nrows, blkM, blkA, blkB);
    }
    k3_scan<<<1, BLOCK, 0, stream>>>(nb, blkM, blkA, blkB, A0, B0);
    k4_dsum<<<nb, BLOCK, 0, stream>>>(Rws, w, x, nrows, A0, B0, bsum);
    k5_final<<<1, BLOCK, 0, stream>>>(bsum, nb, nrows, (float*)d_out);
}